// Round 6
// baseline (382.381 us; speedup 1.0000x reference)
//
#include <hip/hip_runtime.h>
#include <hip/hip_bf16.h>

typedef unsigned int u32;
typedef float f32x4 __attribute__((ext_vector_type(4)));
typedef __bf16 bf16x8 __attribute__((ext_vector_type(8)));

#define BATCH 128
#define NIN   1024
#define DIN   256
#define NC    16
#define DC    32
#define NCOL  512   // NC*DC

__device__ __forceinline__ float bflo(u32 v){ return __uint_as_float(v << 16); }
__device__ __forceinline__ float bfhi(u32 v){ return __uint_as_float(v & 0xffff0000u); }
__device__ __forceinline__ u32 bfround(u32 ua){ return (ua + 0x7fffu + ((ua >> 16) & 1u)) >> 16; }
__device__ __forceinline__ u32 pack2(float a, float b){
    return (bfround(__float_as_uint(a)) & 0xffffu) | (bfround(__float_as_uint(b)) << 16);
}
__device__ __forceinline__ bf16x8 ldfrag(const u32* p){
    return __builtin_bit_cast(bf16x8, *(const uint4*)p);
}

// K0: Wt[n][dpair] (n-major, for s=yd·W) and Wb[d][npair] (d-major, for z=W·o), both bf16 pairs
__global__ __launch_bounds__(256) void k_wconv(const float* __restrict__ W,
                                               u32* __restrict__ Wt, u32* __restrict__ Wb){
    int id = blockIdx.x * 256 + threadIdx.x;        // 0..65535
    {   int n = id >> 7, dp = id & 127;
        Wt[id] = pack2(W[(size_t)(2 * dp) * NCOL + n], W[(size_t)(2 * dp + 1) * NCOL + n]); }
    {   int d = id >> 8, np = id & 255;
        Wb[id] = pack2(W[(size_t)d * NCOL + 2 * np], W[(size_t)d * NCOL + 2 * np + 1]); }
}

// K1: xbf = bf16(x) (row-major, word = dpair) + yd0[b][d] = sum_j x[b][j][d] (iter-0, scale-free)
__global__ __launch_bounds__(256) void k_pre(const float* __restrict__ x, u32* __restrict__ xbf,
                                             float* __restrict__ yd0){
    const int jb = blockIdx.x, b = blockIdx.y, t = threadIdx.x;
    const size_t base = (size_t)b * NIN + jb * 64;
    const float4* xg = (const float4*)(x + base * DIN);
    #pragma unroll
    for (int m = 0; m < 16; m++){
        int id = t + 256 * m;                        // 0..4095 float4s
        int j = id >> 6, dq = id & 63;
        float4 v = xg[id];
        uint2 p; p.x = pack2(v.x, v.y); p.y = pack2(v.z, v.w);
        *(uint2*)&xbf[(base + j) * 128 + dq * 2] = p;
    }
    // column sum (reads hit L2)
    float s = 0.f;
    #pragma unroll 4
    for (int j = 0; j < 64; j++) s += x[(base + j) * DIN + t];
    atomicAdd(&yd0[b * DIN + t], s);
}

// K2: per b: s[n] = sum_d yd[i][d] Wt[n][d]; o = squash(s); z -> zf in MFMA B-fragment order
//     (final pass: write o to out, skip z)
__global__ __launch_bounds__(512) void k_sz(const float* __restrict__ ydIn, int ybs, int yis,
                                            const u32* __restrict__ Wt, const u32* __restrict__ Wb,
                                            uint4* __restrict__ zf, float* __restrict__ out, int final){
    __shared__ float ydl[NC * DIN];   // 16 KB
    __shared__ float ol[NCOL];        // 2 KB
    const int b = blockIdx.x, t = threadIdx.x;
    #pragma unroll
    for (int m = 0; m < 8; m++){
        int idx = t + 512 * m;
        int i = idx >> 8, d = idx & 255;
        ydl[idx] = ydIn[(size_t)b * ybs + i * yis + d];
    }
    __syncthreads();
    // s for n = t
    const int n = t, i = n >> 5;
    const uint4* wr = (const uint4*)&Wt[n * 128];
    const float2* yr = (const float2*)&ydl[i * DIN];
    float s = 0.f;
    #pragma unroll
    for (int w4 = 0; w4 < 32; w4++){
        uint4 u = wr[w4];
        float2 q0 = yr[4 * w4], q1 = yr[4 * w4 + 1], q2 = yr[4 * w4 + 2], q3 = yr[4 * w4 + 3];
        s += bflo(u.x) * q0.x + bfhi(u.x) * q0.y + bflo(u.y) * q1.x + bfhi(u.y) * q1.y
           + bflo(u.z) * q2.x + bfhi(u.z) * q2.y + bflo(u.w) * q3.x + bfhi(u.w) * q3.y;
    }
    // squash over the 32 lanes of capsule i (xor 1..16 stays in 32-group)
    float v = s * s;
    v += __shfl_xor(v, 1); v += __shfl_xor(v, 2); v += __shfl_xor(v, 4);
    v += __shfl_xor(v, 8); v += __shfl_xor(v, 16);
    float o = s / sqrtf(v + 1e-7f);
    if (final){ out[(size_t)b * NCOL + n] = o; return; }
    ol[n] = o;
    __syncthreads();
    // z: thread -> (i2 = t>>5, dpairs dp0..dp0+3), one zf uint4
    const int i2 = t >> 5, dp0 = 4 * (t & 31);
    float oc[DC];
    #pragma unroll
    for (int e = 0; e < 8; e++) *(float4*)&oc[4 * e] = *(const float4*)&ol[i2 * DC + 4 * e];
    u32 zw[4];
    #pragma unroll
    for (int e = 0; e < 4; e++){
        int d0 = 2 * (dp0 + e);
        float za[2];
        #pragma unroll
        for (int h = 0; h < 2; h++){
            const uint4* wbr = (const uint4*)&Wb[(size_t)(d0 + h) * 256 + i2 * 16];
            float acc = 0.f;
            #pragma unroll
            for (int g = 0; g < 4; g++){
                uint4 u = wbr[g];
                acc += bflo(u.x) * oc[8*g+0] + bfhi(u.x) * oc[8*g+1]
                     + bflo(u.y) * oc[8*g+2] + bfhi(u.y) * oc[8*g+3]
                     + bflo(u.z) * oc[8*g+4] + bfhi(u.z) * oc[8*g+5]
                     + bflo(u.w) * oc[8*g+6] + bfhi(u.w) * oc[8*g+7];
            }
            za[h] = acc;
        }
        zw[e] = pack2(za[0], za[1]);
    }
    int ks = dp0 >> 4, q = (dp0 >> 2) & 3;
    zf[(size_t)b * 512 + ks * 64 + q * 16 + i2] = make_uint4(zw[0], zw[1], zw[2], zw[3]);
}

// K3: per (b, 64-j chunk): bb^T = x·z^T (MFMA, z frags from registers), softmax over i in-register,
//     yd += c·x (MFMA via in-LDS transpose). Round-3-verified structure.
__global__ __launch_bounds__(256) void k_route(const u32* __restrict__ xbf, const uint4* __restrict__ zf,
                                               float* __restrict__ yd){
    __shared__ __align__(16) u32 xl [64 * 128];   // 32 KB row-major swizzled
    __shared__ __align__(16) u32 xtl[256 * 32];   // 32 KB transposed [d][jpair] swizzled
    __shared__ __align__(16) u32 cl [16 * 32];    // 2 KB c [i][jpair] swizzled
    const int t = threadIdx.x, chunk = blockIdx.x, b = blockIdx.y;
    const int lane = t & 63, wv = t >> 6;
    const int l15 = lane & 15, q = lane >> 4;

    // z fragments straight to registers
    uint4 zfr[8];
    #pragma unroll
    for (int ks = 0; ks < 8; ks++) zfr[ks] = zf[(size_t)b * 512 + ks * 64 + lane];

    // stage x tile (bf16 already): 2048 uint4, swizzle (w4*4 + 4j) & 127
    {
        const uint4* ug = (const uint4*)&xbf[((size_t)b * NIN + chunk * 64) * 128];
        #pragma unroll
        for (int m = 0; m < 8; m++){
            int id = t + 256 * m;
            int j = id >> 5, w4 = id & 31;
            *(uint4*)&xl[j * 128 + ((4 * w4 + 4 * j) & 127)] = ug[id];
        }
    }
    __syncthreads();

    // GEMM1: bb^T[j][i], wave owns j-tile wv*16..+15, K=256
    f32x4 acc1 = {0.f, 0.f, 0.f, 0.f};
    {
        int jr = wv * 16 + l15;
        #pragma unroll
        for (int ks = 0; ks < 8; ks++){
            bf16x8 a = ldfrag(&xl[jr * 128 + ((ks * 16 + q * 4 + 4 * jr) & 127)]);
            acc1 = __builtin_amdgcn_mfma_f32_16x16x32_bf16(a, __builtin_bit_cast(bf16x8, zfr[ks]), acc1, 0, 0, 0);
        }
    }
    // softmax over i (lanes xor 1,2,4,8), per reg r (one j each)
    float crs[4];
    #pragma unroll
    for (int r = 0; r < 4; r++){
        float v = acc1[r];
        float mx = v;
        mx = fmaxf(mx, __shfl_xor(mx, 1)); mx = fmaxf(mx, __shfl_xor(mx, 2));
        mx = fmaxf(mx, __shfl_xor(mx, 4)); mx = fmaxf(mx, __shfl_xor(mx, 8));
        float e = __expf(v - mx);
        float sm = e;
        sm += __shfl_xor(sm, 1); sm += __shfl_xor(sm, 2);
        sm += __shfl_xor(sm, 4); sm += __shfl_xor(sm, 8);
        crs[r] = e / sm;
    }
    // c -> cl[i][jpair]
    {
        int jp0 = wv * 8 + q * 2;
        uint2 cw; cw.x = pack2(crs[0], crs[1]); cw.y = pack2(crs[2], crs[3]);
        *(uint2*)&cl[l15 * 32 + ((jp0 + 4 * l15) & 31)] = cw;
    }
    // transpose xl -> xtl
    {
        int w = t & 127, jph = (t >> 7) * 16;
        int d0 = 2 * w, d1 = 2 * w + 1;
        #pragma unroll
        for (int g = 0; g < 4; g++){
            u32 o0[4], o1[4];
            #pragma unroll
            for (int e = 0; e < 4; e++){
                int jp = jph + g * 4 + e;
                u32 r0 = xl[(2 * jp)     * 128 + ((w + 8 * jp)     & 127)];
                u32 r1 = xl[(2 * jp + 1) * 128 + ((w + 8 * jp + 4) & 127)];
                o0[e] = (r0 & 0xffffu) | (r1 << 16);
                o1[e] = (r0 >> 16)     | (r1 & 0xffff0000u);
            }
            int jp0 = jph + g * 4;
            *(uint4*)&xtl[d0 * 32 + ((jp0 + 4 * d0) & 31)] = make_uint4(o0[0], o0[1], o0[2], o0[3]);
            *(uint4*)&xtl[d1 * 32 + ((jp0 + 4 * d1) & 31)] = make_uint4(o1[0], o1[1], o1[2], o1[3]);
        }
    }
    __syncthreads();

    // GEMM2: yd[i][d] += c[i][j] x[j][d], K=64; wave owns d-tiles wv*4..+3
    {
        bf16x8 a0 = ldfrag(&cl[l15 * 32 + ((     q * 4 + 4 * l15) & 31)]);
        bf16x8 a1 = ldfrag(&cl[l15 * 32 + ((16 + q * 4 + 4 * l15) & 31)]);
        float* yb = yd + (size_t)b * NC * DIN;
        #pragma unroll
        for (int nt = 0; nt < 4; nt++){
            int d = (wv * 4 + nt) * 16 + l15;
            f32x4 acc2 = {0.f, 0.f, 0.f, 0.f};
            bf16x8 b0 = ldfrag(&xtl[d * 32 + ((     q * 4 + 4 * d) & 31)]);
            acc2 = __builtin_amdgcn_mfma_f32_16x16x32_bf16(a0, b0, acc2, 0, 0, 0);
            bf16x8 b1 = ldfrag(&xtl[d * 32 + ((16 + q * 4 + 4 * d) & 31)]);
            acc2 = __builtin_amdgcn_mfma_f32_16x16x32_bf16(a1, b1, acc2, 0, 0, 0);
            #pragma unroll
            for (int r = 0; r < 4; r++)
                atomicAdd(&yb[(q * 4 + r) * DIN + d], acc2[r]);
        }
    }
}

extern "C" void kernel_launch(void* const* d_in, const int* in_sizes, int n_in,
                              void* d_out, int out_size, void* d_ws, size_t ws_size,
                              hipStream_t stream){
    const float* x = (const float*)d_in[0];    // fp32 [128][1024][256]
    const float* W = (const float*)d_in[1];    // fp32 [256][512]
    float* out = (float*)d_out;                // fp32 [128][16][32]
    float* f = (float*)d_ws;
    float* yd0 = f;                            // 32768 f
    float* yd  = f + 32768;                    // 524288 f
    u32*   Wt  = (u32*)(f + 557056);           // 65536 w
    u32*   Wb  = (u32*)(f + 622592);           // 65536 w
    uint4* zfb = (uint4*)(f + 688128);         // 65536 uint4 = 1 MB
    u32*   xbf = (u32*)(f + 950272);           // 128*1024*128 w = 67 MB

    hipMemsetAsync(yd0, 0, 32768 * sizeof(float), stream);
    k_wconv<<<256, 256, 0, stream>>>(W, Wt, Wb);
    k_pre<<<dim3(16, BATCH), 256, 0, stream>>>(x, xbf, yd0);
    k_sz<<<BATCH, 512, 0, stream>>>(yd0, DIN, 0, Wt, Wb, zfb, out, 0);
    for (int it = 1; it < 4; it++){
        hipMemsetAsync(yd, 0, (size_t)BATCH * NC * DIN * sizeof(float), stream);
        k_route<<<dim3(16, BATCH), 256, 0, stream>>>(xbf, zfb, yd);
        k_sz<<<BATCH, 512, 0, stream>>>(yd, NC * DIN, DIN, Wt, Wb, zfb, out, it == 3 ? 1 : 0);
    }
}

// Round 7
// 340.844 us; speedup vs baseline: 1.1219x; 1.1219x over previous
//
#include <hip/hip_runtime.h>
#include <hip/hip_bf16.h>

typedef unsigned int u32;
typedef float f32x4 __attribute__((ext_vector_type(4)));
typedef __bf16 bf16x8 __attribute__((ext_vector_type(8)));

#define BATCH 128
#define NIN   1024
#define DIN   256
#define NC    16
#define DC    32
#define NCOL  512   // NC*DC

__device__ __forceinline__ float bflo(u32 v){ return __uint_as_float(v << 16); }
__device__ __forceinline__ float bfhi(u32 v){ return __uint_as_float(v & 0xffff0000u); }
__device__ __forceinline__ u32 bfround(u32 ua){ return (ua + 0x7fffu + ((ua >> 16) & 1u)) >> 16; }
__device__ __forceinline__ u32 pack2(float a, float b){
    return (bfround(__float_as_uint(a)) & 0xffffu) | (bfround(__float_as_uint(b)) << 16);
}
__device__ __forceinline__ bf16x8 ldfrag(const u32* p){
    return __builtin_bit_cast(bf16x8, *(const uint4*)p);
}
// rotation swizzle for 16-word (64B) rows: distinct across i-groups (n>>5 term) and j-rows
__device__ __forceinline__ int rot4(int n){ return (n + (n >> 3) + (n >> 5)) & 3; }

// K0: Wt2 = W in MFMA B-fragment order (round-5 verified).
__global__ __launch_bounds__(256) void k_wconv(const float* __restrict__ W, uint4* __restrict__ Wt2){
    int id = blockIdx.x * 256 + threadIdx.x;       // 0..16383
    int l = id & 63, ks = (id >> 6) & 7, ntile = id >> 9;
    int n = ntile * 16 + (l & 15);
    int w0 = ks * 16 + (l >> 4) * 4;
    u32 r[4];
    #pragma unroll
    for (int e = 0; e < 4; e++){
        int w = w0 + e;
        r[e] = pack2(W[(size_t)(2 * w) * NCOL + n], W[(size_t)(2 * w + 1) * NCOL + n]);
    }
    Wt2[id] = make_uint4(r[0], r[1], r[2], r[3]);
}

// K1: u_hat = x@W via MFMA. Layout: word[((b*32 + ch)*512 + n)*16 + wp], ch = 32-j chunk,
//     wp = j-pair within chunk. Iter-0 column sums -> yp0[jb][b][n] (no atomics).
__global__ __launch_bounds__(512) void k_gemm(const float* __restrict__ x, const uint4* __restrict__ Wt2,
                                              u32* __restrict__ uhat, float* __restrict__ yp0){
    __shared__ __align__(16) u32 xl[64 * 128];   // 32 KB, row-swizzled bf16 pairs
    const int t = threadIdx.x, jb = blockIdx.x, b = blockIdx.y;
    const int lane = t & 63, wv = t >> 6;        // 8 waves, wave owns n in [wv*64, wv*64+64)
    const int l15 = lane & 15, q = lane >> 4;

    // B-fragment prefetch for kstep 0 (register pipeline)
    uint4 bnx[4], bc[4];
    #pragma unroll
    for (int nt = 0; nt < 4; nt++)
        bnx[nt] = Wt2[(size_t)(((wv * 4 + nt) * 8 + 0) * 64) + lane];

    // stage x tile 64x256 fp32 -> bf16 pairs (round-3-verified swizzle)
    {
        const float4* xg = (const float4*)(x + ((size_t)b * NIN + jb * 64) * DIN);
        #pragma unroll
        for (int m = 0; m < 4; m++){
            int p = t + 512 * m;                   // float4-pair id 0..2047
            float4 a = xg[2 * p], c = xg[2 * p + 1];
            int j = p >> 5, wq = 4 * (p & 31);
            uint4 v;
            v.x = pack2(a.x, a.y); v.y = pack2(a.z, a.w);
            v.z = pack2(c.x, c.y); v.w = pack2(c.z, c.w);
            *(uint4*)&xl[j * 128 + ((wq + 4 * j) & 127)] = v;
        }
    }
    __syncthreads();

    f32x4 acc[4][4];
    #pragma unroll
    for (int mt = 0; mt < 4; mt++)
        #pragma unroll
        for (int nt = 0; nt < 4; nt++) acc[mt][nt] = (f32x4){0.f, 0.f, 0.f, 0.f};
    #pragma unroll
    for (int ks = 0; ks < 8; ks++){
        bf16x8 af[4];
        #pragma unroll
        for (int mt = 0; mt < 4; mt++){
            int jr = mt * 16 + l15;
            af[mt] = ldfrag(&xl[jr * 128 + ((ks * 16 + q * 4 + 4 * jr) & 127)]);
        }
        #pragma unroll
        for (int nt = 0; nt < 4; nt++) bc[nt] = bnx[nt];
        if (ks < 7){
            #pragma unroll
            for (int nt = 0; nt < 4; nt++)
                bnx[nt] = Wt2[(size_t)(((wv * 4 + nt) * 8 + ks + 1) * 64) + lane];
        }
        #pragma unroll
        for (int mt = 0; mt < 4; mt++)
            #pragma unroll
            for (int nt = 0; nt < 4; nt++)
                acc[mt][nt] = __builtin_amdgcn_mfma_f32_16x16x32_bf16(af[mt], __builtin_bit_cast(bf16x8, bc[nt]), acc[mt][nt], 0, 0, 0);
    }

    // iter-0 y partials: column sums over this block's 64 j rows -> yp0[jb][b][n]
    #pragma unroll
    for (int nt = 0; nt < 4; nt++){
        float v = 0.f;
        #pragma unroll
        for (int mt = 0; mt < 4; mt++)
            #pragma unroll
            for (int r = 0; r < 4; r++) v += acc[mt][nt][r];
        v += __shfl_xor(v, 16);
        v += __shfl_xor(v, 32);
        if (lane < 16)
            yp0[((size_t)jb * BATCH + b) * NCOL + wv * 64 + nt * 16 + lane] = v;
    }

    // direct store, chunk-split: jp = mt*8 + q*2 (+0/1) -> ch = jb*2 + (jp>=16), wp = jp&15
    u32* ub = uhat + (size_t)b * 32 * NCOL * 16;
    #pragma unroll
    for (int nt = 0; nt < 4; nt++){
        int n = wv * 64 + nt * 16 + l15;
        #pragma unroll
        for (int mt = 0; mt < 4; mt++){
            int jp = mt * 8 + q * 2;
            int ch = jb * 2 + (jp >> 4);
            int wp = jp & 15;
            uint2 v;
            v.x = pack2(acc[mt][nt][0], acc[mt][nt][1]);
            v.y = pack2(acc[mt][nt][2], acc[mt][nt][3]);
            *(uint2*)&ub[((size_t)ch * NCOL + n) * 16 + wp] = v;
        }
    }
}

// K2: per (b, 32-j chunk): bb[i][j] = o[i,:]·u[i,j,:]; softmax over i; y-partials -> yp[ch][b][n]
__global__ __launch_bounds__(256) void k_route(const u32* __restrict__ uhat, const float* __restrict__ og,
                                               float* __restrict__ yp){
    __shared__ __align__(16) u32 ul[NCOL * 16];   // 32 KB, rotated 64B rows
    __shared__ float ol[NCOL];                    // 2 KB
    __shared__ float bbc[NC * 33];                // 2.1 KB
    const int ch = blockIdx.x, b = blockIdx.y, t = threadIdx.x;

    ol[t] = og[b * NCOL + t];
    ol[t + 256] = og[b * NCOL + t + 256];
    {
        const uint4* ug = (const uint4*)(uhat + ((size_t)b * 32 + ch) * NCOL * 16);
        uint4* ul4 = (uint4*)ul;
        #pragma unroll
        for (int m = 0; m < 8; m++){
            int id = t + 256 * m;                 // 0..2047
            int n = id >> 2, s = id & 3;
            ul4[n * 4 + ((s + rot4(n)) & 3)] = ug[id];
        }
    }
    __syncthreads();

    // bb: thread (i = t>>4, jq = t&15) -> 2 j's (one u32 word per k), k-loop 32
    {
        int i = t >> 4, jq = t & 15;
        float oc[DC];
        #pragma unroll
        for (int e = 0; e < 8; e++) *(float4*)&oc[4 * e] = *(const float4*)&ol[i * DC + 4 * e];
        float a0 = 0.f, a1 = 0.f;
        #pragma unroll
        for (int k = 0; k < DC; k++){
            int n = i * DC + k;
            u32 v = ul[n * 16 + ((jq + 4 * rot4(n)) & 15)];
            a0 += oc[k] * bflo(v);
            a1 += oc[k] * bfhi(v);
        }
        bbc[i * 33 + 2 * jq]     = a0;
        bbc[i * 33 + 2 * jq + 1] = a1;
    }
    __syncthreads();

    // softmax over i per j (32 j's)
    if (t < 32){
        float m = -1e30f;
        #pragma unroll
        for (int i = 0; i < NC; i++) m = fmaxf(m, bbc[i * 33 + t]);
        float s = 0.f;
        #pragma unroll
        for (int i = 0; i < NC; i++){ float e = __expf(bbc[i * 33 + t] - m); bbc[i * 33 + t] = e; s += e; }
        float inv = 1.f / s;
        #pragma unroll
        for (int i = 0; i < NC; i++) bbc[i * 33 + t] *= inv;
    }
    __syncthreads();

    // y: thread handles n = t and n = t+256; dot over 32 j's; plain store to partials
    #pragma unroll
    for (int h = 0; h < 2; h++){
        int n = t + 256 * h;
        int i = n >> 5;
        float cc[32];
        #pragma unroll
        for (int j = 0; j < 32; j++) cc[j] = bbc[i * 33 + j];
        float s = 0.f;
        const uint4* ul4 = (const uint4*)ul;
        #pragma unroll
        for (int s4 = 0; s4 < 4; s4++){
            uint4 v = ul4[n * 4 + ((s4 + rot4(n)) & 3)];
            int j0 = s4 * 8;
            s += cc[j0+0] * bflo(v.x) + cc[j0+1] * bfhi(v.x)
               + cc[j0+2] * bflo(v.y) + cc[j0+3] * bfhi(v.y)
               + cc[j0+4] * bflo(v.z) + cc[j0+5] * bfhi(v.z)
               + cc[j0+6] * bflo(v.w) + cc[j0+7] * bfhi(v.w);
        }
        yp[((size_t)ch * BATCH + b) * NCOL + n] = s;
    }
}

// K3: y[n] = sum_p partials; o = y/sqrt(||y||^2 + eps) per capsule; write o (and out if final)
__global__ __launch_bounds__(512) void k_sz(const float* __restrict__ yp, int P,
                                            float* __restrict__ og, float* __restrict__ out, int final){
    const int b = blockIdx.x, t = threadIdx.x;
    float s = 0.f;
    for (int p = 0; p < P; p++) s += yp[((size_t)p * BATCH + b) * NCOL + t];
    float v = s * s;
    v += __shfl_xor(v, 1); v += __shfl_xor(v, 2); v += __shfl_xor(v, 4);
    v += __shfl_xor(v, 8); v += __shfl_xor(v, 16);
    float o = s / sqrtf(v + 1e-7f);
    og[b * NCOL + t] = o;
    if (final) out[(size_t)b * NCOL + t] = o;
}

extern "C" void kernel_launch(void* const* d_in, const int* in_sizes, int n_in,
                              void* d_out, int out_size, void* d_ws, size_t ws_size,
                              hipStream_t stream){
    const float* x = (const float*)d_in[0];    // fp32 [128][1024][256]
    const float* W = (const float*)d_in[1];    // fp32 [256][512]
    float* out = (float*)d_out;                // fp32 [128][16][32]
    float* f = (float*)d_ws;
    float* og   = f;                           // 65536 f
    float* yp0  = f + 65536;                   // 16*128*512 = 1048576 f (4 MB)
    float* ypr  = f + 65536 + 1048576;         // 32*128*512 = 2097152 f (8 MB)
    uint4* Wt2  = (uint4*)(f + 65536 + 1048576 + 2097152);   // 256 KB
    u32*   uhat = (u32*)(f + 65536 + 1048576 + 2097152 + 65536);  // 134 MB

    k_wconv<<<64, 256, 0, stream>>>(W, Wt2);
    k_gemm<<<dim3(16, BATCH), 512, 0, stream>>>(x, Wt2, uhat, yp0);
    k_sz<<<BATCH, 512, 0, stream>>>(yp0, 16, og, out, 0);
    for (int it = 1; it < 4; it++){
        k_route<<<dim3(32, BATCH), 256, 0, stream>>>(uhat, og, ypr);
        k_sz<<<BATCH, 512, 0, stream>>>(ypr, 32, og, out, it == 3 ? 1 : 0);
    }
}